// Round 1
// baseline (253.606 us; speedup 1.0000x reference)
//
#include <hip/hip_runtime.h>
#include <hip/hip_bf16.h>

#define B_ 16384
#define NF_ 16
#define VOCAB_ 100000
#define ED_ 32
#define NNUM_ 13
#define E_ 8
#define T_ 2
#define H0_ 512
#define H1_ 256
#define TH_ 128
#define D0_ 525
#define K0P 576   // padded K for layer 0 (multiple of 64)

#define BM 128
#define BN 128
#define BKK 64

typedef __bf16 bf16x8 __attribute__((ext_vector_type(8)));
typedef float  f32x4  __attribute__((ext_vector_type(4)));
typedef int    i32x4  __attribute__((ext_vector_type(4)));

// ---------------- embedding + concat + pad + cast ----------------
__global__ __launch_bounds__(192) void k_embed(const int* __restrict__ cat,
                                               const float* __restrict__ num,
                                               const float* __restrict__ emb,
                                               __hip_bfloat16* __restrict__ x) {
  int b = blockIdx.x;
  int t = threadIdx.x;
  const int* crow = cat + b * NF_;
#pragma unroll
  for (int i = 0; i < 3; ++i) {
    int d = t + i * 192;  // 0..575
    float v;
    if (d < 512) {
      int f = d >> 5, c = d & 31;
      v = emb[((long long)(f * VOCAB_ + crow[f])) * ED_ + c];
    } else if (d < D0_) {
      v = num[b * NNUM_ + (d - 512)];
    } else {
      v = 0.f;
    }
    x[(long long)b * K0P + d] = __float2bfloat16(v);
  }
}

// ---------------- weight transpose + pad + cast: W[E][K][N] f32 -> Wp[E][N][KP] bf16 ----------------
__global__ __launch_bounds__(256) void k_wprep(const float* __restrict__ W,
                                               __hip_bfloat16* __restrict__ Wp,
                                               int K, int N, int KP) {
  __shared__ float tile[64][65];
  int k0 = blockIdx.x * 64, n0 = blockIdx.y * 64, e = blockIdx.z;
  int tx = threadIdx.x & 63, ty = threadIdx.x >> 6;
  for (int r = ty; r < 64; r += 4) {
    int k = k0 + r;
    tile[r][tx] = (k < K) ? W[((long long)e * K + k) * N + n0 + tx] : 0.f;
  }
  __syncthreads();
  for (int r = ty; r < 64; r += 4) {
    int n = n0 + r;
    Wp[((long long)e * N + n) * KP + k0 + tx] = __float2bfloat16(tile[tx][r]);
  }
}

// ---------------- BN param folding ----------------
__global__ void k_prep_small(const float* b0, const float* g0, const float* be0,
                             const float* m0, const float* v0,
                             const float* b1, const float* g1, const float* be1,
                             const float* m1, const float* v1,
                             const float* bt1, const float* tg, const float* tb,
                             const float* tm, const float* tv,
                             float* scale0, float* ebias0, float* scale1, float* ebias1,
                             float* tscale, float* tbias) {
  int i = blockIdx.x * 256 + threadIdx.x;
  if (i < H0_) scale0[i] = g0[i] * rsqrtf(v0[i] + 1e-5f);
  if (i < H1_) scale1[i] = g1[i] * rsqrtf(v1[i] + 1e-5f);
  if (i < T_ * TH_) {
    float s = tg[i] * rsqrtf(tv[i] + 1e-5f);
    tscale[i] = s;
    tbias[i] = (bt1[i] - tm[i]) * s + tb[i];
  }
  if (i < E_ * H0_) {
    int n = i & (H0_ - 1);
    float s = g0[n] * rsqrtf(v0[n] + 1e-5f);
    ebias0[i] = (b0[i] - m0[n]) * s + be0[n];
  }
  if (i < E_ * H1_) {
    int n = i & (H1_ - 1);
    float s = g1[n] * rsqrtf(v1[n] + 1e-5f);
    ebias1[i] = (b1[i] - m1[n]) * s + be1[n];
  }
}

// ---------------- gate logits + softmax over 8 experts ----------------
__global__ __launch_bounds__(256) void k_gates(const __hip_bfloat16* __restrict__ x,
                                               const float* __restrict__ Wg,
                                               const float* __restrict__ bg,
                                               float* __restrict__ gates) {
  int gidx = blockIdx.x * 256 + threadIdx.x;
  int b = gidx >> 4, te = gidx & 15;
  int t = te >> 3, e = te & 7;
  const __hip_bfloat16* xr = x + (long long)b * K0P;
  const float* wg = Wg + ((long long)t * D0_) * E_ + e;
  float acc = bg[t * E_ + e];
  int k = 0;
  for (; k + 8 <= D0_; k += 8) {
    bf16x8 xv = *reinterpret_cast<const bf16x8*>(xr + k);
#pragma unroll
    for (int j = 0; j < 8; ++j)
      acc += (float)xv[j] * wg[(long long)(k + j) * E_];
  }
  for (; k < D0_; ++k) acc += __bfloat162float(xr[k]) * wg[(long long)k * E_];
  float mx = acc;
#pragma unroll
  for (int o = 1; o < 8; o <<= 1) mx = fmaxf(mx, __shfl_xor(mx, o));
  float p = __expf(acc - mx);
  float s = p;
#pragma unroll
  for (int o = 1; o < 8; o <<= 1) s += __shfl_xor(s, o);
  gates[((long long)t * B_ + b) * E_ + e] = p / s;
}

// ---------------- grouped GEMM + BN + ReLU -> bf16 ----------------
// A: [e?][M][lda] bf16 row-major.  Bw: [e][N][ldb] bf16 (output-feature-major).
// C[e][M][N] = relu( (A @ Bw^T) * scale[n] + ebias[e][n] )
__global__ __launch_bounds__(256) void k_gemm(
    const __hip_bfloat16* __restrict__ Aall, long long strideAe, int lda,
    const __hip_bfloat16* __restrict__ Ball, long long strideBe, int ldb,
    __hip_bfloat16* __restrict__ Call, long long strideCe, int N,
    const float* __restrict__ scale, const float* __restrict__ ebias, int strideEb,
    int K) {
  __shared__ __align__(16) char As[BM * 128];
  __shared__ __align__(16) char Bs[BN * 128];

  const int e = blockIdx.z;
  const char* A = reinterpret_cast<const char*>(Aall + (long long)e * strideAe +
                                                (long long)blockIdx.x * BM * lda);
  const char* Bw = reinterpret_cast<const char*>(Ball + (long long)e * strideBe +
                                                 (long long)blockIdx.y * BN * ldb);
  const int ldab = lda * 2, ldbb = ldb * 2;

  const int tid = threadIdx.x;
  const int lane = tid & 63;
  const int wid = tid >> 6;
  const int wr = wid >> 1, wc = wid & 1;
  const int srow = tid >> 3;
  const int sc16 = (tid & 7) * 16;  // unswizzled 16B chunk offset within row

  i32x4 ra[4], rb[4];
  const int nk = K / BKK;

#pragma unroll
  for (int it = 0; it < 4; ++it) {
    int row = srow + it * 32;
    ra[it] = *reinterpret_cast<const i32x4*>(A + (long long)row * ldab + sc16);
    rb[it] = *reinterpret_cast<const i32x4*>(Bw + (long long)row * ldbb + sc16);
  }

  f32x4 acc[4][4];
#pragma unroll
  for (int m = 0; m < 4; ++m)
#pragma unroll
    for (int n = 0; n < 4; ++n) acc[m][n] = (f32x4){0.f, 0.f, 0.f, 0.f};

  for (int ks = 0; ks < nk; ++ks) {
    __syncthreads();
#pragma unroll
    for (int it = 0; it < 4; ++it) {
      int row = srow + it * 32;
      int byt = row * 128 + (sc16 ^ ((row & 7) << 4));
      *reinterpret_cast<i32x4*>(As + byt) = ra[it];
      *reinterpret_cast<i32x4*>(Bs + byt) = rb[it];
    }
    if (ks + 1 < nk) {
#pragma unroll
      for (int it = 0; it < 4; ++it) {
        int row = srow + it * 32;
        ra[it] = *reinterpret_cast<const i32x4*>(A + (long long)row * ldab + (ks + 1) * 128 + sc16);
        rb[it] = *reinterpret_cast<const i32x4*>(Bw + (long long)row * ldbb + (ks + 1) * 128 + sc16);
      }
    }
    __syncthreads();
#pragma unroll
    for (int kk = 0; kk < 2; ++kk) {
      bf16x8 af[4], bfr[4];
      int kb = kk * 64 + (lane >> 4) * 16;
#pragma unroll
      for (int m = 0; m < 4; ++m) {
        int row = wr * 64 + m * 16 + (lane & 15);
        af[m] = *reinterpret_cast<const bf16x8*>(As + row * 128 + (kb ^ ((row & 7) << 4)));
      }
#pragma unroll
      for (int n = 0; n < 4; ++n) {
        int row = wc * 64 + n * 16 + (lane & 15);
        bfr[n] = *reinterpret_cast<const bf16x8*>(Bs + row * 128 + (kb ^ ((row & 7) << 4)));
      }
#pragma unroll
      for (int m = 0; m < 4; ++m)
#pragma unroll
        for (int n = 0; n < 4; ++n)
          acc[m][n] = __builtin_amdgcn_mfma_f32_16x16x32_bf16(af[m], bfr[n], acc[m][n], 0, 0, 0);
    }
  }

  __hip_bfloat16* C = Call + (long long)e * strideCe;
  const float* eb = ebias + e * strideEb;
  const int m0 = blockIdx.x * BM, n0 = blockIdx.y * BN;
#pragma unroll
  for (int n = 0; n < 4; ++n) {
    int col = n0 + wc * 64 + n * 16 + (lane & 15);
    float s = scale[col];
    float bb = eb[col];
#pragma unroll
    for (int m = 0; m < 4; ++m) {
      int rowb = m0 + wr * 64 + m * 16 + (lane >> 4) * 4;
#pragma unroll
      for (int i = 0; i < 4; ++i) {
        float v = fmaxf(acc[m][n][i] * s + bb, 0.f);
        C[(long long)(rowb + i) * N + col] = __float2bfloat16(v);
      }
    }
  }
}

// ---------------- fused combine + tower MLP + sigmoid ----------------
// grid: (B/64, T), block 256 (4 waves, each wave owns 16 rows)
__global__ __launch_bounds__(256) void k_tower(
    const __hip_bfloat16* __restrict__ h1, const float* __restrict__ gates,
    const float* __restrict__ Wt1, const float* __restrict__ Wt2,
    const float* __restrict__ bt2, const float* __restrict__ tscale,
    const float* __restrict__ tbias, float* __restrict__ out) {
  __shared__ __align__(16) char Ws[TH_ * 512];  // Ws[h][k] bf16, swizzled
  const int t = blockIdx.y;
  const int tid = threadIdx.x;
  const int lane = tid & 63, wv = tid >> 6;

  // stage Wt1[t][k][h] f32 -> Ws[h][k] bf16 (swizzled), coalesced reads over h
  for (int it = 0; it < 16; ++it) {
    int idx = it * 256 + tid;
    int h = idx & 127, kc = idx >> 7;  // kc in 0..31 (chunks of 8 k)
    bf16x8 v;
#pragma unroll
    for (int j = 0; j < 8; ++j)
      v[j] = (__bf16)Wt1[((long long)t * H1_ + kc * 8 + j) * TH_ + h];
    int byt = h * 512 + ((kc * 16) ^ ((h & 7) << 4));
    *reinterpret_cast<bf16x8*>(Ws + byt) = v;
  }

  const int row = blockIdx.x * 64 + wv * 16 + (lane & 15);
  const int g4 = lane >> 4;

  float gt[8];
  {
    const float* gp = gates + ((long long)t * B_ + row) * E_;
#pragma unroll
    for (int j = 0; j < 8; ++j) gt[j] = gp[j];
  }

  // combine: fea[row][k] for this lane's A-fragment slots, k = c*32 + g4*8 + j
  float fa[8][8];
#pragma unroll
  for (int c = 0; c < 8; ++c)
#pragma unroll
    for (int j = 0; j < 8; ++j) fa[c][j] = 0.f;

#pragma unroll
  for (int ee = 0; ee < 8; ++ee) {
    const char* hp = reinterpret_cast<const char*>(h1) +
                     (((long long)ee * B_ + row) * H1_ + g4 * 8) * 2;
    float g = gt[ee];
#pragma unroll
    for (int c = 0; c < 8; ++c) {
      bf16x8 hv = *reinterpret_cast<const bf16x8*>(hp + c * 64);
#pragma unroll
      for (int j = 0; j < 8; ++j) fa[c][j] += g * (float)hv[j];
    }
  }
  bf16x8 af[8];
#pragma unroll
  for (int c = 0; c < 8; ++c)
#pragma unroll
    for (int j = 0; j < 8; ++j) af[c][j] = (__bf16)fa[c][j];

  __syncthreads();

  f32x4 acc[8];
#pragma unroll
  for (int n = 0; n < 8; ++n) acc[n] = (f32x4){0.f, 0.f, 0.f, 0.f};
#pragma unroll
  for (int c = 0; c < 8; ++c) {
    int kb = c * 64 + g4 * 16;
#pragma unroll
    for (int n = 0; n < 8; ++n) {
      int hrow = n * 16 + (lane & 15);
      bf16x8 bv = *reinterpret_cast<const bf16x8*>(Ws + hrow * 512 + (kb ^ ((hrow & 7) << 4)));
      acc[n] = __builtin_amdgcn_mfma_f32_16x16x32_bf16(af[c], bv, acc[n], 0, 0, 0);
    }
  }

  float part[4] = {0.f, 0.f, 0.f, 0.f};
#pragma unroll
  for (int n = 0; n < 8; ++n) {
    int col = n * 16 + (lane & 15);
    float s = tscale[t * TH_ + col], bb = tbias[t * TH_ + col], w2 = Wt2[t * TH_ + col];
#pragma unroll
    for (int i = 0; i < 4; ++i)
      part[i] += fmaxf(acc[n][i] * s + bb, 0.f) * w2;
  }
#pragma unroll
  for (int o = 1; o < 16; o <<= 1) {
#pragma unroll
    for (int i = 0; i < 4; ++i) part[i] += __shfl_xor(part[i], o);
  }
  if ((lane & 15) == 0) {
    int rbase = blockIdx.x * 64 + wv * 16 + g4 * 4;
    float b2 = bt2[t];
#pragma unroll
    for (int i = 0; i < 4; ++i) {
      float z = part[i] + b2;
      out[(long long)t * B_ + rbase + i] = 1.f / (1.f + __expf(-z));
    }
  }
}

extern "C" void kernel_launch(void* const* d_in, const int* in_sizes, int n_in,
                              void* d_out, int out_size, void* d_ws, size_t ws_size,
                              hipStream_t stream) {
  const int*   cat = (const int*)d_in[0];
  const float* num = (const float*)d_in[1];
  const float* emb = (const float*)d_in[3];
  const float* W0  = (const float*)d_in[4];
  const float* b0  = (const float*)d_in[5];
  const float* g0  = (const float*)d_in[6];
  const float* be0 = (const float*)d_in[7];
  const float* m0  = (const float*)d_in[8];
  const float* v0  = (const float*)d_in[9];
  const float* W1  = (const float*)d_in[10];
  const float* b1  = (const float*)d_in[11];
  const float* g1  = (const float*)d_in[12];
  const float* be1 = (const float*)d_in[13];
  const float* m1  = (const float*)d_in[14];
  const float* v1  = (const float*)d_in[15];
  const float* Wg  = (const float*)d_in[16];
  const float* bg  = (const float*)d_in[17];
  const float* Wt1 = (const float*)d_in[18];
  const float* bt1 = (const float*)d_in[19];
  const float* tg  = (const float*)d_in[20];
  const float* tb  = (const float*)d_in[21];
  const float* tm  = (const float*)d_in[22];
  const float* tv  = (const float*)d_in[23];
  const float* Wt2 = (const float*)d_in[24];
  const float* bt2 = (const float*)d_in[25];
  float* out = (float*)d_out;

  char* ws = (char*)d_ws;
  if (ws_size < 228094976ULL) return;  // layout below needs ~228 MB

  __hip_bfloat16* x_bf = (__hip_bfloat16*)(ws + 0ULL);           // 16384*576*2
  __hip_bfloat16* W0p  = (__hip_bfloat16*)(ws + 18874368ULL);    // 8*512*576*2
  __hip_bfloat16* W1p  = (__hip_bfloat16*)(ws + 23592960ULL);    // 8*256*512*2
  float* gates   = (float*)(ws + 25690112ULL);                   // 2*16384*8*4
  float* scale0  = (float*)(ws + 26738688ULL);
  float* ebias0  = (float*)(ws + 26740736ULL);
  float* scale1  = (float*)(ws + 26757120ULL);
  float* ebias1  = (float*)(ws + 26758144ULL);
  float* tscale  = (float*)(ws + 26766336ULL);
  float* tbias   = (float*)(ws + 26767360ULL);
  __hip_bfloat16* h0 = (__hip_bfloat16*)(ws + 26768384ULL);      // 8*16384*512*2
  __hip_bfloat16* h1 = (__hip_bfloat16*)(ws + 160986112ULL);     // 8*16384*256*2

  // weight prep + BN folding
  k_wprep<<<dim3(K0P / 64, H0_ / 64, E_), 256, 0, stream>>>(W0, W0p, D0_, H0_, K0P);
  k_wprep<<<dim3(H0_ / 64, H1_ / 64, E_), 256, 0, stream>>>(W1, W1p, H0_, H1_, H0_);
  k_prep_small<<<16, 256, 0, stream>>>(b0, g0, be0, m0, v0, b1, g1, be1, m1, v1,
                                       bt1, tg, tb, tm, tv,
                                       scale0, ebias0, scale1, ebias1, tscale, tbias);
  // embedding + concat
  k_embed<<<B_, 192, 0, stream>>>(cat, num, emb, x_bf);
  // gates
  k_gates<<<B_ * 16 / 256, 256, 0, stream>>>(x_bf, Wg, bg, gates);
  // layer 0: [B,576] x [E,512,576]^T -> h0 [E,B,512]
  k_gemm<<<dim3(B_ / BM, H0_ / BN, E_), 256, 0, stream>>>(
      x_bf, 0LL, K0P, W0p, (long long)H0_ * K0P, K0P,
      h0, (long long)B_ * H0_, H0_, scale0, ebias0, H0_, K0P);
  // layer 1: h0 [E,B,512] x [E,256,512]^T -> h1 [E,B,256]
  k_gemm<<<dim3(B_ / BM, H1_ / BN, E_), 256, 0, stream>>>(
      h0, (long long)B_ * H0_, H0_, W1p, (long long)H1_ * H0_, H0_,
      h1, (long long)B_ * H1_, H1_, scale1, ebias1, H1_, H0_);
  // combine + tower + sigmoid
  k_tower<<<dim3(B_ / 64, T_), 256, 0, stream>>>(h1, gates, Wt1, Wt2, bt2,
                                                 tscale, tbias, out);
}